// Round 1
// baseline (2883.876 us; speedup 1.0000x reference)
//
#include <hip/hip_runtime.h>

#define EMBED  512
#define HIDDEN 1024
#define G4     4096      // 4*HIDDEN
#define VOCAB  50257
#define BATCH  64
#define TSTEPS 18
#define MROWS  (BATCH*TSTEPS)   // 1152

typedef __bf16 bf16x8 __attribute__((ext_vector_type(8)));
typedef float  f32x4  __attribute__((ext_vector_type(4)));

// workspace layout (float offsets)
#define WS_HA 0
#define WS_HB 65536          // 64*1024
#define WS_C  131072
#define WS_XB 196608         // 64*4096 floats -> ends at 458752 floats
#define WS_HS_BYTES 1835008  // byte offset of hs (bf16, 1152*1024 elements)

// ---------------- init: zero hA, hB, c (196608 floats) ----------------
__global__ __launch_bounds__(256) void k_init(float* ws) {
    int i = blockIdx.x * blockDim.x + threadIdx.x;   // 49152 float4s
    ((float4*)ws)[i] = make_float4(0.f, 0.f, 0.f, 0.f);
}

// ---------------- x_proj: xb[b][r] = b_ih[r]+b_hh[r] + feat[b,:]·W_ih[r,:] ----------------
__global__ __launch_bounds__(256) void k_xproj(const float* __restrict__ feat,
                                               const float* __restrict__ W_ih,
                                               const float* __restrict__ b_ih,
                                               const float* __restrict__ b_hh,
                                               float* __restrict__ xb) {
    __shared__ float fsh[16][EMBED];
    const int tx = threadIdx.x;
    const int rc = blockIdx.x;        // 0..255, 16 rows each
    const int b0 = blockIdx.y * 16;   // 0..3 -> batch chunk
    {
        int row = tx >> 4, seg = tx & 15;  // 16 threads/row, 32 floats each
        const float4* src = (const float4*)(feat + (b0 + row) * EMBED + seg * 32);
        float4* dst = (float4*)(&fsh[row][seg * 32]);
        #pragma unroll
        for (int c = 0; c < 8; ++c) dst[c] = src[c];
    }
    __syncthreads();
    const int jl = tx & 15, bl = tx >> 4;
    const int r = rc * 16 + jl;
    const int b = b0 + bl;
    const float4* w  = (const float4*)(W_ih + (size_t)r * EMBED);
    const float4* h4 = (const float4*)(&fsh[bl][0]);
    float acc = 0.f;
    #pragma unroll 4
    for (int k = 0; k < EMBED / 4; ++k) {
        float4 wv = w[k], hv = h4[k];
        acc += wv.x * hv.x + wv.y * hv.y + wv.z * hv.z + wv.w * hv.w;
    }
    xb[b * G4 + r] = acc + b_ih[r] + b_hh[r];
}

// ---------------- LSTM step (fp32): gates + cell, writes h fp32 + bf16 row ----------------
__global__ __launch_bounds__(256) void k_step(const float* __restrict__ h_in,
                                              float* __restrict__ h_out,
                                              float* __restrict__ c,
                                              const float* __restrict__ xb,
                                              const float* __restrict__ W_hh,
                                              __bf16* __restrict__ hs, int t) {
    __shared__ float hsh[16][HIDDEN];   // 64 KB
    const int tx = threadIdx.x;
    const int jc = blockIdx.x;          // 0..63, 16 j each
    const int b0 = blockIdx.y * 16;     // 0..3 -> batch chunk of 16
    {
        int row = tx >> 4, seg = tx & 15;  // 16 threads/row, 64 floats each
        const float4* src = (const float4*)(h_in + (b0 + row) * HIDDEN + seg * 64);
        float4* dst = (float4*)(&hsh[row][seg * 64]);
        #pragma unroll
        for (int cc = 0; cc < 16; ++cc) dst[cc] = src[cc];
    }
    __syncthreads();
    const int jl = tx & 15, bl = tx >> 4;
    const int j = jc * 16 + jl;
    const int b = b0 + bl;
    const float4* w0 = (const float4*)(W_hh + (size_t)(j) * HIDDEN);
    const float4* w1 = (const float4*)(W_hh + (size_t)(j + HIDDEN) * HIDDEN);
    const float4* w2 = (const float4*)(W_hh + (size_t)(j + 2 * HIDDEN) * HIDDEN);
    const float4* w3 = (const float4*)(W_hh + (size_t)(j + 3 * HIDDEN) * HIDDEN);
    const float4* h4 = (const float4*)(&hsh[bl][0]);
    float a0 = 0.f, a1 = 0.f, a2 = 0.f, a3 = 0.f;
    #pragma unroll 4
    for (int k = 0; k < HIDDEN / 4; ++k) {
        float4 hv = h4[k];
        float4 v0 = w0[k]; a0 += v0.x*hv.x + v0.y*hv.y + v0.z*hv.z + v0.w*hv.w;
        float4 v1 = w1[k]; a1 += v1.x*hv.x + v1.y*hv.y + v1.z*hv.z + v1.w*hv.w;
        float4 v2 = w2[k]; a2 += v2.x*hv.x + v2.y*hv.y + v2.z*hv.z + v2.w*hv.w;
        float4 v3 = w3[k]; a3 += v3.x*hv.x + v3.y*hv.y + v3.z*hv.z + v3.w*hv.w;
    }
    const float gi = a0 + xb[b * G4 + j];
    const float gf = a1 + xb[b * G4 + HIDDEN + j];
    const float gg = a2 + xb[b * G4 + 2 * HIDDEN + j];
    const float go = a3 + xb[b * G4 + 3 * HIDDEN + j];
    const float i_ = 1.f / (1.f + expf(-gi));
    const float f_ = 1.f / (1.f + expf(-gf));
    const float g_ = tanhf(gg);
    const float o_ = 1.f / (1.f + expf(-go));
    const int ci = b * HIDDEN + j;
    const float cn = f_ * c[ci] + i_ * g_;
    c[ci] = cn;
    const float hn = o_ * tanhf(cn);
    h_out[ci] = hn;
    hs[(size_t)(b * TSTEPS + t) * HIDDEN + j] = (__bf16)hn;
}

// ---------------- classifier GEMM: out[m][v] = hs[m,:]·W_fc[v,:] + b_fc[v] ----------------
// C = A(1152x1024 bf16) * B(1024x50257, from fp32 W_fc^T), MFMA 16x16x32 bf16.
// Block tile 128m x 128n, 4 waves in 2x2, each wave 4x4 tiles of 16x16.
__device__ inline bf16x8 cvt2bf8(float4 a, float4 b) {
    bf16x8 v;
    v[0] = (__bf16)a.x; v[1] = (__bf16)a.y; v[2] = (__bf16)a.z; v[3] = (__bf16)a.w;
    v[4] = (__bf16)b.x; v[5] = (__bf16)b.y; v[6] = (__bf16)b.z; v[7] = (__bf16)b.w;
    return v;
}

#define LPITCH 40   // bf16 elements per LDS row (32 data + 8 pad; 80B keeps 16B align, 2-way banks)

__global__ __launch_bounds__(256) void k_fc(const __bf16* __restrict__ hs,
                                            const float* __restrict__ W_fc,
                                            const float* __restrict__ b_fc,
                                            float* __restrict__ out) {
    __shared__ __bf16 Ash[128 * LPITCH];
    __shared__ __bf16 Bsh[128 * LPITCH];
    const int tx = threadIdx.x;
    const int nb = blockIdx.x * 128;
    const int mb = blockIdx.y * 128;

    // staging: thread -> (row 0..127, half 0..1), 16 elements (k) per half
    const int srow = tx >> 1;
    const int half = tx & 1;
    const __bf16* aSrc = hs + (size_t)(mb + srow) * HIDDEN + half * 16;
    const int nclamp = min(nb + srow, VOCAB - 1);
    const float4* bSrc = (const float4*)(W_fc + (size_t)nclamp * HIDDEN + half * 16);
    __bf16* aDst = &Ash[srow * LPITCH + half * 16];
    __bf16* bDst = &Bsh[srow * LPITCH + half * 16];

    const int lane = tx & 63;
    const int wave = tx >> 6;
    const int q = lane >> 4;
    const int r = lane & 15;
    const int wm = (wave >> 1) * 64;
    const int wn = (wave & 1) * 64;

    const __bf16* aF[4];
    const __bf16* bF[4];
    #pragma unroll
    for (int i = 0; i < 4; ++i) aF[i] = &Ash[(wm + i * 16 + r) * LPITCH + q * 8];
    #pragma unroll
    for (int j = 0; j < 4; ++j) bF[j] = &Bsh[(wn + j * 16 + r) * LPITCH + q * 8];

    f32x4 acc[4][4];
    #pragma unroll
    for (int i = 0; i < 4; ++i)
        #pragma unroll
        for (int j = 0; j < 4; ++j)
            acc[i][j] = (f32x4){0.f, 0.f, 0.f, 0.f};

    // prefetch k0 = 0
    bf16x8 a0p = *(const bf16x8*)aSrc;
    bf16x8 a1p = *(const bf16x8*)(aSrc + 8);
    float4 f0p = bSrc[0], f1p = bSrc[1], f2p = bSrc[2], f3p = bSrc[3];
    aSrc += 32; bSrc += 8;

    for (int k0 = 0; k0 < HIDDEN; k0 += 32) {
        *(bf16x8*)aDst = a0p;
        *(bf16x8*)(aDst + 8) = a1p;
        *(bf16x8*)bDst = cvt2bf8(f0p, f1p);
        *(bf16x8*)(bDst + 8) = cvt2bf8(f2p, f3p);
        __syncthreads();
        if (k0 + 32 < HIDDEN) {   // prefetch next slab under MFMA compute
            a0p = *(const bf16x8*)aSrc;
            a1p = *(const bf16x8*)(aSrc + 8);
            f0p = bSrc[0]; f1p = bSrc[1]; f2p = bSrc[2]; f3p = bSrc[3];
            aSrc += 32; bSrc += 8;
        }
        bf16x8 av[4], bv[4];
        #pragma unroll
        for (int i = 0; i < 4; ++i) av[i] = *(const bf16x8*)aF[i];
        #pragma unroll
        for (int j = 0; j < 4; ++j) bv[j] = *(const bf16x8*)bF[j];
        #pragma unroll
        for (int i = 0; i < 4; ++i)
            #pragma unroll
            for (int j = 0; j < 4; ++j)
                acc[i][j] = __builtin_amdgcn_mfma_f32_16x16x32_bf16(av[i], bv[j], acc[i][j], 0, 0, 0);
        __syncthreads();
    }

    // epilogue: C/D layout col=lane&15, row=(lane>>4)*4+reg
    #pragma unroll
    for (int j = 0; j < 4; ++j) {
        const int v = nb + wn + j * 16 + r;
        if (v < VOCAB) {
            const float bias = b_fc[v];
            #pragma unroll
            for (int i = 0; i < 4; ++i) {
                const int m0 = mb + wm + i * 16 + q * 4;
                float* op = out + (size_t)m0 * VOCAB + v;
                op[0]                 = acc[i][j][0] + bias;
                op[(size_t)VOCAB]     = acc[i][j][1] + bias;
                op[(size_t)VOCAB * 2] = acc[i][j][2] + bias;
                op[(size_t)VOCAB * 3] = acc[i][j][3] + bias;
            }
        }
    }
}

extern "C" void kernel_launch(void* const* d_in, const int* in_sizes, int n_in,
                              void* d_out, int out_size, void* d_ws, size_t ws_size,
                              hipStream_t stream) {
    const float* feat = (const float*)d_in[0];
    const float* W_ih = (const float*)d_in[1];
    const float* W_hh = (const float*)d_in[2];
    const float* b_ih = (const float*)d_in[3];
    const float* b_hh = (const float*)d_in[4];
    const float* W_fc = (const float*)d_in[5];
    const float* b_fc = (const float*)d_in[6];
    float* out = (float*)d_out;

    float* ws = (float*)d_ws;
    float* hA = ws + WS_HA;
    float* hB = ws + WS_HB;
    float* c  = ws + WS_C;
    float* xb = ws + WS_XB;
    __bf16* hs = (__bf16*)((char*)d_ws + WS_HS_BYTES);

    k_init<<<192, 256, 0, stream>>>(ws);
    k_xproj<<<dim3(256, 4), 256, 0, stream>>>(feat, W_ih, b_ih, b_hh, xb);
    for (int t = 0; t < TSTEPS; ++t) {
        const float* hi = (t & 1) ? hB : hA;
        float*       ho = (t & 1) ? hA : hB;
        k_step<<<dim3(64, 4), 256, 0, stream>>>(hi, ho, c, xb, W_hh, hs, t);
    }
    k_fc<<<dim3(393, 9), 256, 0, stream>>>(hs, W_fc, b_fc, out);
}

// Round 2
// 958.473 us; speedup vs baseline: 3.0088x; 3.0088x over previous
//
#include <hip/hip_runtime.h>

#define EMBED  512
#define HIDDEN 1024
#define G4     4096      // 4*HIDDEN
#define VOCAB  50257
#define BATCH  64
#define TSTEPS 18
#define MROWS  (BATCH*TSTEPS)   // 1152

typedef __bf16 bf16x8 __attribute__((ext_vector_type(8)));
typedef __bf16 bf16x4 __attribute__((ext_vector_type(4)));
typedef float  f32x4  __attribute__((ext_vector_type(4)));

// ---------------- workspace layout (byte offsets) ----------------
// hA bf16 64x1024 :       0 .. 131072
// hB bf16 64x1024 :  131072 .. 262144
// c  f32  64x1024 :  262144 .. 524288
// xb f32  64x4096 :  524288 .. 1572864
// hs bf16 1152x1024: 1572864 .. 3932160
// Whh bf16 4096x1024: 3932160 .. 12320768
#define WS_HA_B   0
#define WS_HB_B   131072
#define WS_C_B    262144
#define WS_XB_B   524288
#define WS_HS_B   1572864
#define WS_WHH_B  3932160

// ---------------- init: zero hA, hB, c (524288 bytes = 32768 float4) ----------------
__global__ __launch_bounds__(256) void k_init(float4* ws) {
    int i = blockIdx.x * blockDim.x + threadIdx.x;   // 128 blocks * 256
    ws[i] = make_float4(0.f, 0.f, 0.f, 0.f);
}

// ---------------- convert W_hh fp32 -> bf16 (4096*1024 elems, 8/thread) ----------------
__global__ __launch_bounds__(256) void k_cvt(const float* __restrict__ src,
                                             __bf16* __restrict__ dst) {
    int i = (blockIdx.x * blockDim.x + threadIdx.x) * 8;   // 2048 blocks
    float4 a = *(const float4*)(src + i);
    float4 b = *(const float4*)(src + i + 4);
    bf16x8 v;
    v[0] = (__bf16)a.x; v[1] = (__bf16)a.y; v[2] = (__bf16)a.z; v[3] = (__bf16)a.w;
    v[4] = (__bf16)b.x; v[5] = (__bf16)b.y; v[6] = (__bf16)b.z; v[7] = (__bf16)b.w;
    *(bf16x8*)(dst + i) = v;
}

// ---------------- x_proj: xb[b][r] = b_ih[r]+b_hh[r] + feat[b,:]·W_ih[r,:] ----------------
__global__ __launch_bounds__(256) void k_xproj(const float* __restrict__ feat,
                                               const float* __restrict__ W_ih,
                                               const float* __restrict__ b_ih,
                                               const float* __restrict__ b_hh,
                                               float* __restrict__ xb) {
    __shared__ float fsh[16][EMBED];
    const int tx = threadIdx.x;
    const int rc = blockIdx.x;        // 0..255, 16 rows each
    const int b0 = blockIdx.y * 16;   // 0..3 -> batch chunk
    {
        int row = tx >> 4, seg = tx & 15;  // 16 threads/row, 32 floats each
        const float4* src = (const float4*)(feat + (b0 + row) * EMBED + seg * 32);
        float4* dst = (float4*)(&fsh[row][seg * 32]);
        #pragma unroll
        for (int c = 0; c < 8; ++c) dst[c] = src[c];
    }
    __syncthreads();
    const int jl = tx & 15, bl = tx >> 4;
    const int r = rc * 16 + jl;
    const int b = b0 + bl;
    const float4* w  = (const float4*)(W_ih + (size_t)r * EMBED);
    const float4* h4 = (const float4*)(&fsh[bl][0]);
    float acc = 0.f;
    #pragma unroll 4
    for (int k = 0; k < EMBED / 4; ++k) {
        float4 wv = w[k], hv = h4[k];
        acc += wv.x * hv.x + wv.y * hv.y + wv.z * hv.z + wv.w * hv.w;
    }
    xb[b * G4 + r] = acc + b_ih[r] + b_hh[r];
}

// ---------------- LSTM step via MFMA ----------------
// Block = j-strip of 16 (grid 64), 4 waves split K (256 each).
// Wave computes partial gates[4g][64m][16j] for its K-quarter, frags loaded
// directly from global (h bf16, Whh bf16). LDS exchange for K-reduce + gate
// fusion; epilogue does activations + c/h update, writes h bf16 + hs row.
#define PJT 17   // padded j-stride for partials

__global__ __launch_bounds__(256) void k_step(const __bf16* __restrict__ h_in,
                                              __bf16* __restrict__ h_out,
                                              float* __restrict__ c,
                                              const float* __restrict__ xb,
                                              const __bf16* __restrict__ Whh,
                                              __bf16* __restrict__ hs, int t) {
    __shared__ float part[16 * 64 * PJT];   // [w*4+g][m][PJT] = 69632 B
    const int tx   = threadIdx.x;
    const int wave = tx >> 6;
    const int lane = tx & 63;
    const int q    = lane >> 4;      // k-quad
    const int r    = lane & 15;      // row within 16
    const int j0   = blockIdx.x * 16;
    const int kb   = wave * 256;     // this wave's K range

    f32x4 acc[4][4];   // [m-tile i][gate g]
    #pragma unroll
    for (int i = 0; i < 4; ++i)
        #pragma unroll
        for (int g = 0; g < 4; ++g)
            acc[i][g] = (f32x4){0.f, 0.f, 0.f, 0.f};

    // A rows: batch m = i*16 + r ; B rows: gate g at Whh[g*1024 + j0 + r]
    const __bf16* aBase = h_in + (size_t)r * HIDDEN + kb + q * 8;
    const __bf16* bBase = Whh + (size_t)(j0 + r) * HIDDEN + kb + q * 8;

    #pragma unroll 2
    for (int s = 0; s < 8; ++s) {
        const int ko = s * 32;
        bf16x8 av[4], bv[4];
        #pragma unroll
        for (int i = 0; i < 4; ++i)
            av[i] = *(const bf16x8*)(aBase + (size_t)i * 16 * HIDDEN + ko);
        #pragma unroll
        for (int g = 0; g < 4; ++g)
            bv[g] = *(const bf16x8*)(bBase + (size_t)g * 1024 * HIDDEN + ko);
        #pragma unroll
        for (int i = 0; i < 4; ++i)
            #pragma unroll
            for (int g = 0; g < 4; ++g)
                acc[i][g] = __builtin_amdgcn_mfma_f32_16x16x32_bf16(av[i], bv[g], acc[i][g], 0, 0, 0);
    }

    // write partials: C layout col(lane&15)=j, row(q*4+reg)=m-within-tile
    #pragma unroll
    for (int i = 0; i < 4; ++i)
        #pragma unroll
        for (int g = 0; g < 4; ++g)
            #pragma unroll
            for (int reg = 0; reg < 4; ++reg)
                part[((wave * 4 + g) * 64 + i * 16 + q * 4 + reg) * PJT + r] = acc[i][g][reg];
    __syncthreads();

    // reduce + LSTM cell: thread -> (jl = tx&15, m0 = tx>>4), 4 m each
    const int jl = tx & 15;
    const int m0 = tx >> 4;
    #pragma unroll
    for (int mi = 0; mi < 4; ++mi) {
        const int m = mi * 16 + m0;
        float gsum[4];
        #pragma unroll
        for (int g = 0; g < 4; ++g) {
            float s = xb[m * G4 + g * 1024 + j0 + jl];
            #pragma unroll
            for (int w = 0; w < 4; ++w)
                s += part[((w * 4 + g) * 64 + m) * PJT + jl];
            gsum[g] = s;
        }
        const float i_ = 1.f / (1.f + expf(-gsum[0]));
        const float f_ = 1.f / (1.f + expf(-gsum[1]));
        const float g_ = tanhf(gsum[2]);
        const float o_ = 1.f / (1.f + expf(-gsum[3]));
        const int ci = m * HIDDEN + j0 + jl;
        const float cn = f_ * c[ci] + i_ * g_;
        c[ci] = cn;
        const float hn = o_ * tanhf(cn);
        const __bf16 hb = (__bf16)hn;
        h_out[ci] = hb;
        hs[(size_t)(m * TSTEPS + t) * HIDDEN + j0 + jl] = hb;
    }
}

// ---------------- classifier GEMM: out[m][v] = hs[m,:]·W_fc[v,:] + b_fc[v] ----------------
__device__ inline bf16x8 cvt2bf8(float4 a, float4 b) {
    bf16x8 v;
    v[0] = (__bf16)a.x; v[1] = (__bf16)a.y; v[2] = (__bf16)a.z; v[3] = (__bf16)a.w;
    v[4] = (__bf16)b.x; v[5] = (__bf16)b.y; v[6] = (__bf16)b.z; v[7] = (__bf16)b.w;
    return v;
}

#define LPITCH 40   // bf16 elems per LDS row (32 data + 8 pad)
#define NBLK 393    // ceil(50257/128)
#define MBLK 9      // 1152/128

__global__ __launch_bounds__(256) void k_fc(const __bf16* __restrict__ hs,
                                            const float* __restrict__ W_fc,
                                            const float* __restrict__ b_fc,
                                            float* __restrict__ out) {
    __shared__ __bf16 Ash[128 * LPITCH];
    __shared__ __bf16 Bsh[128 * LPITCH];
    const int tx = threadIdx.x;
    // m-major swizzle: consecutive blocks share the same n (W_fc chunk) -> L3 reuse
    const int bid = blockIdx.x;
    const int mb = (bid % MBLK) * 128;
    const int nb = (bid / MBLK) * 128;

    const int srow = tx >> 1;
    const int half = tx & 1;
    const __bf16* aSrc = hs + (size_t)(mb + srow) * HIDDEN + half * 16;
    const int nclamp = min(nb + srow, VOCAB - 1);
    const float4* bSrc = (const float4*)(W_fc + (size_t)nclamp * HIDDEN + half * 16);
    __bf16* aDst = &Ash[srow * LPITCH + half * 16];
    __bf16* bDst = &Bsh[srow * LPITCH + half * 16];

    const int lane = tx & 63;
    const int wave = tx >> 6;
    const int q = lane >> 4;
    const int r = lane & 15;
    const int wm = (wave >> 1) * 64;
    const int wn = (wave & 1) * 64;

    const __bf16* aF[4];
    const __bf16* bF[4];
    #pragma unroll
    for (int i = 0; i < 4; ++i) aF[i] = &Ash[(wm + i * 16 + r) * LPITCH + q * 8];
    #pragma unroll
    for (int j = 0; j < 4; ++j) bF[j] = &Bsh[(wn + j * 16 + r) * LPITCH + q * 8];

    f32x4 acc[4][4];
    #pragma unroll
    for (int i = 0; i < 4; ++i)
        #pragma unroll
        for (int j = 0; j < 4; ++j)
            acc[i][j] = (f32x4){0.f, 0.f, 0.f, 0.f};

    bf16x8 a0p = *(const bf16x8*)aSrc;
    bf16x8 a1p = *(const bf16x8*)(aSrc + 8);
    float4 f0p = bSrc[0], f1p = bSrc[1], f2p = bSrc[2], f3p = bSrc[3];
    aSrc += 32; bSrc += 8;

    for (int k0 = 0; k0 < HIDDEN; k0 += 32) {
        *(bf16x8*)aDst = a0p;
        *(bf16x8*)(aDst + 8) = a1p;
        *(bf16x8*)bDst = cvt2bf8(f0p, f1p);
        *(bf16x8*)(bDst + 8) = cvt2bf8(f2p, f3p);
        __syncthreads();
        if (k0 + 32 < HIDDEN) {
            a0p = *(const bf16x8*)aSrc;
            a1p = *(const bf16x8*)(aSrc + 8);
            f0p = bSrc[0]; f1p = bSrc[1]; f2p = bSrc[2]; f3p = bSrc[3];
            aSrc += 32; bSrc += 8;
        }
        bf16x8 av[4], bv[4];
        #pragma unroll
        for (int i = 0; i < 4; ++i) av[i] = *(const bf16x8*)aF[i];
        #pragma unroll
        for (int j = 0; j < 4; ++j) bv[j] = *(const bf16x8*)bF[j];
        #pragma unroll
        for (int i = 0; i < 4; ++i)
            #pragma unroll
            for (int j = 0; j < 4; ++j)
                acc[i][j] = __builtin_amdgcn_mfma_f32_16x16x32_bf16(av[i], bv[j], acc[i][j], 0, 0, 0);
        __syncthreads();
    }

    #pragma unroll
    for (int j = 0; j < 4; ++j) {
        const int v = nb + wn + j * 16 + r;
        if (v < VOCAB) {
            const float bias = b_fc[v];
            #pragma unroll
            for (int i = 0; i < 4; ++i) {
                const int m0 = mb + wm + i * 16 + q * 4;
                float* op = out + (size_t)m0 * VOCAB + v;
                op[0]                 = acc[i][j][0] + bias;
                op[(size_t)VOCAB]     = acc[i][j][1] + bias;
                op[(size_t)VOCAB * 2] = acc[i][j][2] + bias;
                op[(size_t)VOCAB * 3] = acc[i][j][3] + bias;
            }
        }
    }
}

extern "C" void kernel_launch(void* const* d_in, const int* in_sizes, int n_in,
                              void* d_out, int out_size, void* d_ws, size_t ws_size,
                              hipStream_t stream) {
    const float* feat = (const float*)d_in[0];
    const float* W_ih = (const float*)d_in[1];
    const float* W_hh = (const float*)d_in[2];
    const float* b_ih = (const float*)d_in[3];
    const float* b_hh = (const float*)d_in[4];
    const float* W_fc = (const float*)d_in[5];
    const float* b_fc = (const float*)d_in[6];
    float* out = (float*)d_out;

    char* wsb = (char*)d_ws;
    __bf16* hA  = (__bf16*)(wsb + WS_HA_B);
    __bf16* hB  = (__bf16*)(wsb + WS_HB_B);
    float*  c   = (float*)(wsb + WS_C_B);
    float*  xb  = (float*)(wsb + WS_XB_B);
    __bf16* hs  = (__bf16*)(wsb + WS_HS_B);
    __bf16* Whh = (__bf16*)(wsb + WS_WHH_B);

    k_init<<<128, 256, 0, stream>>>((float4*)wsb);
    k_cvt<<<2048, 256, 0, stream>>>(W_hh, Whh);
    k_xproj<<<dim3(256, 4), 256, 0, stream>>>(feat, W_ih, b_ih, b_hh, xb);
    for (int t = 0; t < TSTEPS; ++t) {
        const __bf16* hi = (t & 1) ? hB : hA;
        __bf16*       ho = (t & 1) ? hA : hB;
        k_step<<<64, 256, 0, stream>>>(hi, ho, c, xb, Whh, hs, t);
    }
    k_fc<<<NBLK * MBLK, 256, 0, stream>>>(hs, W_fc, b_fc, out);
}